// Round 17
// baseline (121.638 us; speedup 1.0000x reference)
//
#include <hip/hip_runtime.h>

#define BAND 16
#define NITER (BAND + 4)
#define NSLOT 1024
#define SLABW 256

__global__ __launch_bounds__(64) void nms_loss_kernel(
    const float* __restrict__ tl, const float* __restrict__ pl,
    double* __restrict__ acc_d, float* __restrict__ acc_f,
    int H, int W)
{
    // whole-band LDS staging via global_load_lds (one 1KB DMA per row)
    __shared__ __align__(16) float t_s[20][264];   // t rows y0-2..y0+17, local col 4+k <-> gx slabc+k
    __shared__ __align__(16) float p_s[18][264];   // p rows y0-1..y0+16 (reflected)

    const int y0   = blockIdx.x * BAND;
    const int slab = blockIdx.y;
    const int ch   = blockIdx.z;
    const int slabc = slab << 8;
    const int nslab = W / SLABW;
    const float* tc = tl + (size_t)ch * H * W;
    const float* pc = pl + (size_t)ch * H * W;
    const int tid = threadIdx.x;               // 0..63, one wave
    const int c0  = slabc + (tid << 2);        // 4 output columns per thread
    const bool eL = (c0 == 0), eR = (c0 == W - 4);
    const float eL2 = eL ? 2.f : 0.f, eR2 = eR ? 2.f : 0.f;
    const bool hl = (tid == 0) && (slab > 0);              // seam-left lane
    const bool hr = (tid == 63) && (slab < nslab - 1);     // seam-right lane
    const bool hseam = hl || hr;
    const int hcol = hl ? (slabc - 2) : (slabc + SLABW);   // float2 base for seam halo

    // ===== prologue: issue ALL band loads as LDS DMA (no VGPR round-trip) =====
    for (int rr = 0; rr < 20; ++rr) {
        int tr = min(max(y0 - 2 + rr, 0), H - 1);
        const float* ga = tc + (size_t)tr * W + slabc + (tid << 2);
        __builtin_amdgcn_global_load_lds(
            (const __attribute__((address_space(1))) void*)ga,
            (__attribute__((address_space(3))) void*)&t_s[rr][4], 16, 0, 0);
    }
    for (int rr = 0; rr < 18; ++rr) {
        int pr = y0 - 1 + rr; pr = pr < 0 ? -pr : (pr >= H ? 2 * H - 2 - pr : pr);
        const float* ga = pc + (size_t)pr * W + slabc + (tid << 2);
        __builtin_amdgcn_global_load_lds(
            (const __attribute__((address_space(1))) void*)ga,
            (__attribute__((address_space(3))) void*)&p_s[rr][4], 16, 0, 0);
    }
    asm volatile("s_waitcnt vmcnt(0)" ::: "memory");
    __builtin_amdgcn_sched_barrier(0);

    // register rings: P (5 rows x 4 px), e (3 rows x 6 cols), mask (3 rows x 4 px)
    float P1h[5][4], P2h[5][4], P3h[5][4];
    float eh[3][6], tch[3][4];
    float t12[12], p12[12];

    // LOADROW(I): pull row I's window from LDS; seam halo from global (2 lanes);
    // true-edge ghosts via the R15-validated cndmask fixups.
    #define LOADROW(I) {                                                            \
        const float* trow = &t_s[(I)][(tid << 2) + 2];                               \
        float2 q0 = *(const float2*)(trow);                                          \
        float2 q1 = *(const float2*)(trow + 2);                                      \
        float2 q2 = *(const float2*)(trow + 4);                                      \
        float2 q3 = *(const float2*)(trow + 6);                                      \
        t12[2]=q0.x; t12[3]=q0.y; t12[4]=q1.x; t12[5]=q1.y;                          \
        t12[6]=q2.x; t12[7]=q2.y; t12[8]=q3.x; t12[9]=q3.y;                          \
        const int prr = (I) >= 2 ? (I) - 2 : 0;                                      \
        const float* prow = &p_s[prr][(tid << 2) + 2];                               \
        q0 = *(const float2*)(prow);                                                 \
        q1 = *(const float2*)(prow + 2);                                             \
        q2 = *(const float2*)(prow + 4);                                             \
        q3 = *(const float2*)(prow + 6);                                             \
        p12[2]=q0.x; p12[3]=q0.y; p12[4]=q1.x; p12[5]=q1.y;                          \
        p12[6]=q2.x; p12[7]=q2.y; p12[8]=q3.x; p12[9]=q3.y;                          \
        if (hseam) {                                                                 \
            int tr_ = min(max(y0 - 2 + (I), 0), H - 1);                              \
            float2 th_ = *(const float2*)(tc + (size_t)tr_ * W + hcol);              \
            int pr_ = y0 - 1 + prr; pr_ = pr_ < 0 ? -pr_ : (pr_ >= H ? 2*H-2-pr_ : pr_); \
            float2 ph_ = *(const float2*)(pc + (size_t)pr_ * W + hcol);              \
            if (hl) { t12[2]=th_.x; t12[3]=th_.y; p12[3]=ph_.y; }                    \
            else    { t12[8]=th_.x; t12[9]=th_.y; p12[8]=ph_.x; }                    \
        }                                                                            \
        t12[2] = eL ? t12[5] : t12[2];   /* ghost(-2)=t1 */                          \
        t12[3] = eL ? t12[4] : t12[3];   /* ghost(-1)=t0 */                          \
        t12[8] = eR ? t12[7] : t12[8];   /* ghost(W)  =t(W-1) */                     \
        t12[9] = eR ? t12[6] : t12[9];   /* ghost(W+1)=t(W-2) */                     \
        p12[3] = eL ? p12[5] : p12[3];   /* e reflect(-1)=col 1 */                   \
        p12[8] = eR ? p12[6] : p12[8]; } /* e reflect(W)=col W-2 */

    LOADROW(0)

    float partial = 0.f;

    #pragma unroll
    for (int i = 0; i < NITER; ++i) {
        const int sP = i % 5, sE = i % 3;

        // ---- consume pending row (branch-free, validated R15 arithmetic) ----
        #pragma unroll
        for (int j = 0; j < 4; ++j) {
            float a0 = t12[j+2], a1 = t12[j+3], a2 = t12[j+4], a3 = t12[j+5], a4 = t12[j+6];
            float s04 = a0 + a4, s13 = a1 + a3;
            P1h[sP][j] = fmaf(-2.f, a2, s04);                       // hdd
            P3h[sP][j] = fmaf(6.f, a2, fmaf(4.f, s13, s04));        // hss
            P2h[sP][j] = fmaf(2.f, a3 - a1, a4 - a0);               // hds
            tch[sE][j] = a2;
        }
        P1h[sP][0] = fmaf(eL2, t12[4] - t12[5], P1h[sP][0]);
        P1h[sP][3] = fmaf(eR2, t12[7] - t12[6], P1h[sP][3]);
        #pragma unroll
        for (int m = 0; m < 6; ++m) eh[sE][m] = __expf(0.1f * p12[m+3]);

        // ---- issue next-row LDS reads (latency hides under output phase) ----
        if (i + 1 < NITER) LOADROW(i + 1)

        // ---- output row y = y0 + i - 4 ----
        if (i >= 4) {
            const int y = y0 + i - 4;
            const int s0=(i-4)%5, s1=(i-3)%5, s2=(i-2)%5, s3=(i-1)%5, s4=i%5;
            const int et=(i-2)%3, em=(i-1)%3, eb=i%3;   // e rows y-1, y, y+1
            const bool ytop = (y == 0), ybot = (y == H - 1);
            #pragma unroll
            for (int j = 0; j < 4; ++j) {
                float a04 = P1h[s0][j] + P1h[s4][j], a13 = P1h[s1][j] + P1h[s3][j];
                float xx = fmaf(6.f, P1h[s2][j], fmaf(4.f, a13, a04));   // wss
                float xy = fmaf(2.f, P2h[s3][j] - P2h[s1][j], P2h[s4][j] - P2h[s0][j]); // wsd
                float yy = fmaf(-2.f, P3h[s2][j], P3h[s0][j] + P3h[s4][j]);             // wdd
                if (ytop) {
                    xx += P1h[s3][j] - P1h[s2][j];
                    xy += P2h[s3][j] - P2h[s2][j];
                    yy += P3h[s2][j] - P3h[s3][j];
                } else if (ybot) {
                    xx += P1h[s1][j] - P1h[s2][j];
                    xy += P2h[s2][j] - P2h[s1][j];
                    yy += P3h[s2][j] - P3h[s1][j];
                }
                if (tch[et][j] > 0.f) {          // mask at row y
                    float den = xx + 6.4e-6f;     // 64*(grad_xx+1e-7)
                    float sa  = 6.4e-6f - xy;     // 64*(1e-7-grad_xy)
                    float ax = fabsf(den), ay = fabsf(yy);
                    bool isH = ay < 0.41421356f * ax;    // tan(22.5)
                    bool isV = ay >= 2.41421356f * ax;   // tan(67.5)
                    bool qp  = ((yy * sa) * den) > 0.f;  // sign of q
                    float ec = eh[em][j + 1];            // e col x
                    float n1 = isH ? eh[em][j + 2] : (isV ? eh[eb][j + 1] : (qp ? eh[eb][j] : eh[eb][j + 2]));
                    float n2 = isH ? eh[em][j]     : (isV ? eh[et][j + 1] : (qp ? eh[et][j + 2] : eh[et][j]));
                    partial += __logf(__fdividef(ec, ec + n1 + n2 + 1e-7f));
                }
            }
        }
    }

    // ---- wave reduction + spread atomics (single wave, no barriers) ----
    for (int off = 32; off > 0; off >>= 1)
        partial += __shfl_down(partial, off, 64);
    if (tid == 0) {
        int fid = (blockIdx.z * gridDim.y + blockIdx.y) * gridDim.x + blockIdx.x;
        if (acc_d) atomicAdd(&acc_d[fid & (NSLOT - 1)], (double)partial);
        else       atomicAdd(acc_f, partial);
    }
}

__global__ void finalize_kernel(const double* acc_d, float* out,
                                int use_double, float inv_b)
{
    if (use_double) {
        int l = threadIdx.x;
        double s = 0.0;
        for (int i = l; i < NSLOT; i += 64) s += acc_d[i];
        for (int off = 32; off > 0; off >>= 1) s += __shfl_down(s, off, 64);
        if (l == 0) out[0] = (float)(-s * (double)inv_b);
    } else {
        if (threadIdx.x == 0) out[0] = -out[0] * inv_b;
    }
}

extern "C" void kernel_launch(void* const* d_in, const int* in_sizes, int n_in,
                              void* d_out, int out_size, void* d_ws, size_t ws_size,
                              hipStream_t stream)
{
    const float* tl = (const float*)d_in[0];
    const float* pl = (const float*)d_in[1];
    float* out = (float*)d_out;

    const int H = 512, W = 512, B = 4;

    double* acc_d = nullptr;
    float* acc_f = nullptr;
    int use_double = 0;
    if (ws_size >= NSLOT * sizeof(double)) {
        acc_d = (double*)d_ws;
        use_double = 1;
        hipMemsetAsync(acc_d, 0, NSLOT * sizeof(double), stream);
    } else {
        acc_f = out;
        hipMemsetAsync(out, 0, sizeof(float), stream);
    }

    // 32 bands x 2 slabs x 76 channels = 4864 single-wave blocks, band fully LDS-staged
    dim3 grid(H / BAND, W / SLABW, 76);
    nms_loss_kernel<<<grid, 64, 0, stream>>>(tl, pl, acc_d, acc_f, H, W);
    finalize_kernel<<<1, 64, 0, stream>>>(acc_d, out, use_double, 1.0f / (float)B);
}

// Round 18
// 63.129 us; speedup vs baseline: 1.9268x; 1.9268x over previous
//
#include <hip/hip_runtime.h>

#define BAND 16
#define NITER (BAND + 4)
#define NSLOT 1024

__global__ __launch_bounds__(256) void nms_loss_kernel(
    const float* __restrict__ tl, const float* __restrict__ pl,
    double* __restrict__ acc_d, float* __restrict__ acc_f,
    int H, int W)
{
    const int y0  = blockIdx.x * BAND;
    const int ch  = blockIdx.y;
    const float* tc = tl + (size_t)ch * H * W;
    const float* pc = pl + (size_t)ch * H * W;
    const int tid  = threadIdx.x;
    const int lane = tid & 63;
    const int c0 = tid << 1;                    // this thread's 2 output columns
    const int oa = min(max(c0 - 2, 0), W - 2);  // clamped float2 bases
    const int oc = min(c0 + 2, W - 2);
    const bool xedge = (c0 == 0) || (c0 == W - 2);

    // register rings: P (5 rows), e (3 rows), t-center/mask (3 rows)
    float P1h[5][2], P2h[5][2], P3h[5][2];
    float eh[3][4], tch[3][2];
    // two pending-row slots: A = even rows, B = odd rows (paired issue)
    float tA[6], pA[6], tB[6], pB[6];

    // row(I): t row y0-2+I (clamp), p row y0-3+I (reflect)
    #define LOADROW(I, T6, P6) {                                                   \
        int tr_ = y0 - 2 + (I); tr_ = min(max(tr_, 0), H - 1);                      \
        int pr_ = y0 - 3 + (I); pr_ = pr_ < 0 ? -pr_ : (pr_ >= H ? 2*H-2-pr_ : pr_);\
        const float* tb_ = tc + (size_t)tr_ * W;                                    \
        const float* pb_ = pc + (size_t)pr_ * W;                                    \
        float2 a_ = *(const float2*)(tb_ + oa), b_ = *(const float2*)(tb_ + c0),    \
               c_ = *(const float2*)(tb_ + oc);                                     \
        T6[0]=a_.x; T6[1]=a_.y; T6[2]=b_.x; T6[3]=b_.y; T6[4]=c_.x; T6[5]=c_.y;     \
        a_ = *(const float2*)(pb_ + oa); b_ = *(const float2*)(pb_ + c0);           \
        c_ = *(const float2*)(pb_ + oc);                                            \
        P6[0]=a_.x; P6[1]=a_.y; P6[2]=b_.x; P6[3]=b_.y; P6[4]=c_.x; P6[5]=c_.y; }

    // consume pending row into P/e/mask rings (verified R12 arithmetic)
    #define CONSUME(T6, P6, SP, SE) {                                               \
        const int sP = (SP), sE = (SE);                                             \
        if (!xedge) {                                                               \
            float s04 = T6[0] + T6[4], s13 = T6[1] + T6[3];                         \
            P1h[sP][0] = fmaf(-2.f, T6[2], s04);                                    \
            P3h[sP][0] = fmaf(6.f, T6[2], fmaf(4.f, s13, s04));                     \
            P2h[sP][0] = fmaf(2.f, T6[3] - T6[1], T6[4] - T6[0]);                   \
            float s04b = T6[1] + T6[5], s13b = T6[2] + T6[4];                       \
            P1h[sP][1] = fmaf(-2.f, T6[3], s04b);                                   \
            P3h[sP][1] = fmaf(6.f, T6[3], fmaf(4.f, s13b, s04b));                   \
            P2h[sP][1] = fmaf(2.f, T6[4] - T6[2], T6[5] - T6[1]);                   \
        } else if (c0 == 0) {                                                       \
            P1h[sP][0] = T6[4] - T6[3];                                             \
            P2h[sP][0] = fmaf(-2.f, T6[2], T6[3] + T6[4]);                          \
            P3h[sP][0] = fmaf(10.f, T6[2], fmaf(5.f, T6[3], T6[4]));                \
            P1h[sP][1] = fmaf(-2.f, T6[3], T6[2] + T6[5]);                          \
            P2h[sP][1] = fmaf(-3.f, T6[2], fmaf(2.f, T6[4], T6[5]));                \
            P3h[sP][1] = fmaf(5.f, T6[2], fmaf(6.f, T6[3], fmaf(4.f, T6[4], T6[5])));\
        } else {                                                                    \
            P1h[sP][0] = fmaf(-2.f, T6[2], T6[0] + T6[3]);                          \
            P2h[sP][0] = fmaf(3.f, T6[3], fmaf(-2.f, T6[1], -T6[0]));               \
            P3h[sP][0] = fmaf(5.f, T6[3], fmaf(6.f, T6[2], fmaf(4.f, T6[1], T6[0])));\
            P1h[sP][1] = T6[1] - T6[2];                                             \
            P2h[sP][1] = fmaf(2.f, T6[3], -T6[1] - T6[2]);                          \
            P3h[sP][1] = fmaf(10.f, T6[3], fmaf(5.f, T6[2], T6[1]));                \
        }                                                                           \
        tch[sE][0] = T6[2]; tch[sE][1] = T6[3];                                     \
        eh[sE][0] = __expf(0.1f * P6[1]);                                           \
        eh[sE][1] = __expf(0.1f * P6[2]);                                           \
        eh[sE][2] = __expf(0.1f * P6[3]);                                           \
        eh[sE][3] = __expf(0.1f * P6[4]); }

    // output row y = y0 + I - 4 (interior vertical + validated y-edge fixups)
    #define OUTPUT(I) if ((I) >= 4) {                                               \
        const int y = y0 + (I) - 4;                                                 \
        const int s0=((I)-4)%5, s1=((I)-3)%5, s2=((I)-2)%5, s3=((I)-1)%5, s4=(I)%5; \
        const int et=((I)-2)%3, em=((I)-1)%3, ebq=(I)%3;                            \
        const bool ytop = (y == 0), ybot = (y == H - 1);                            \
        _Pragma("unroll")                                                           \
        for (int j = 0; j < 2; ++j) {                                               \
            float a04 = P1h[s0][j] + P1h[s4][j], a13 = P1h[s1][j] + P1h[s3][j];     \
            float xx = fmaf(6.f, P1h[s2][j], fmaf(4.f, a13, a04));                  \
            float xy = fmaf(2.f, P2h[s3][j] - P2h[s1][j], P2h[s4][j] - P2h[s0][j]); \
            float yy = fmaf(-2.f, P3h[s2][j], P3h[s0][j] + P3h[s4][j]);             \
            if (ytop) {                                                             \
                xx += P1h[s3][j] - P1h[s2][j];                                      \
                xy += P2h[s3][j] - P2h[s2][j];                                      \
                yy += P3h[s2][j] - P3h[s3][j];                                      \
            } else if (ybot) {                                                      \
                xx += P1h[s1][j] - P1h[s2][j];                                      \
                xy += P2h[s2][j] - P2h[s1][j];                                      \
                yy += P3h[s2][j] - P3h[s1][j];                                      \
            }                                                                       \
            if (tch[et][j] > 0.f) {                                                 \
                float den = xx + 6.4e-6f;                                           \
                float sa  = 6.4e-6f - xy;                                           \
                float ax = fabsf(den), ay = fabsf(yy);                              \
                bool isH = ay < 0.41421356f * ax;                                   \
                bool isV = ay >= 2.41421356f * ax;                                  \
                bool qp  = ((yy * sa) * den) > 0.f;                                 \
                float ec = eh[em][j + 1];                                           \
                float n1 = isH ? eh[em][j + 2] : (isV ? eh[ebq][j + 1]              \
                                : (qp ? eh[ebq][j] : eh[ebq][j + 2]));              \
                float n2 = isH ? eh[em][j]     : (isV ? eh[et][j + 1]               \
                                : (qp ? eh[et][j + 2] : eh[et][j]));                \
                partial += __logf(__fdividef(ec, ec + n1 + n2 + 1e-7f));            \
            }                                                                       \
        } }

    LOADROW(0, tA, pA)
    LOADROW(1, tB, pB)

    float partial = 0.f;

    // paired-row loop: chain depth 10 instead of 20, 12-load bursts
    #pragma unroll
    for (int ii = 0; ii < NITER; ii += 2) {
        CONSUME(tA, pA, ii % 5, ii % 3)
        CONSUME(tB, pB, (ii + 1) % 5, (ii + 1) % 3)
        if (ii + 2 < NITER) LOADROW(ii + 2, tA, pA)
        if (ii + 3 < NITER) LOADROW(ii + 3, tB, pB)
        OUTPUT(ii)
        OUTPUT(ii + 1)
    }

    // ---- block reduction: wave shuffle + spread atomics ----
    for (int off = 32; off > 0; off >>= 1)
        partial += __shfl_down(partial, off, 64);
    if (lane == 0) {
        int fid = (blockIdx.y * gridDim.x + blockIdx.x) * 4 + (tid >> 6);
        if (acc_d) atomicAdd(&acc_d[fid & (NSLOT - 1)], (double)partial);
        else       atomicAdd(acc_f, partial);
    }
}

__global__ void finalize_kernel(const double* acc_d, float* out,
                                int use_double, float inv_b)
{
    if (use_double) {
        int l = threadIdx.x;
        double s = 0.0;
        for (int i = l; i < NSLOT; i += 64) s += acc_d[i];
        for (int off = 32; off > 0; off >>= 1) s += __shfl_down(s, off, 64);
        if (l == 0) out[0] = (float)(-s * (double)inv_b);
    } else {
        if (threadIdx.x == 0) out[0] = -out[0] * inv_b;
    }
}

extern "C" void kernel_launch(void* const* d_in, const int* in_sizes, int n_in,
                              void* d_out, int out_size, void* d_ws, size_t ws_size,
                              hipStream_t stream)
{
    const float* tl = (const float*)d_in[0];
    const float* pl = (const float*)d_in[1];
    float* out = (float*)d_out;

    const int H = 512, W = 512, B = 4;

    double* acc_d = nullptr;
    float* acc_f = nullptr;
    int use_double = 0;
    if (ws_size >= NSLOT * sizeof(double)) {
        acc_d = (double*)d_ws;
        use_double = 1;
        hipMemsetAsync(acc_d, 0, NSLOT * sizeof(double), stream);
    } else {
        acc_f = out;
        hipMemsetAsync(out, 0, sizeof(float), stream);
    }

    dim3 grid(H / BAND, 76, 1);   // 32 bands x 76 channels, 512 cols/block
    nms_loss_kernel<<<grid, 256, 0, stream>>>(tl, pl, acc_d, acc_f, H, W);
    finalize_kernel<<<1, 64, 0, stream>>>(acc_d, out, use_double, 1.0f / (float)B);
}

// Round 19
// 61.332 us; speedup vs baseline: 1.9833x; 1.0293x over previous
//
#include <hip/hip_runtime.h>

#define BAND 16
#define NITER (BAND + 4)   // 20 = 4 rounds x 5 (P-ring period)
#define NSLOT 1024

__global__ __launch_bounds__(256) void nms_loss_kernel(
    const float* __restrict__ tl, const float* __restrict__ pl,
    double* __restrict__ acc_d, float* __restrict__ acc_f,
    int H, int W)
{
    const int y0  = blockIdx.x * BAND;
    const int ch  = blockIdx.y;
    const float* tc = tl + (size_t)ch * H * W;
    const float* pc = pl + (size_t)ch * H * W;
    const int tid  = threadIdx.x;
    const int lane = tid & 63;
    const int c0 = tid << 1;                    // 2 output columns per thread
    const int oa = min(max(c0 - 2, 0), W - 2);  // clamped float2 bases
    const int oc = min(c0 + 2, W - 2);
    const bool eL = (c0 == 0), eR = (c0 == W - 2);
    const float eL2 = eL ? 2.f : 0.f, eR2 = eR ? 2.f : 0.f;

    // rings: P (period 5, index static per unrolled copy), e/mask (period 3, shifted)
    float P1h[5][2], P2h[5][2], P3h[5][2];
    float eh[3][4], tch[3][2];
    float t6[6], p6[6];

    // t row y0-2+I (clamp), p row y0-3+I (reflect); t-edge ghosts via swap
    // (slot(-2)<-t1, slot(-1)<-t0 left; slot(W)<-t(W-1), slot(W+1)<-t(W-2) right);
    // p-edge reflect ghosts are automatic from the clamped base (R12-validated).
    #define LOADROW(I) {                                                            \
        int tr_ = y0 - 2 + (I); tr_ = min(max(tr_, 0), H - 1);                       \
        int pr_ = y0 - 3 + (I); pr_ = pr_ < 0 ? -pr_ : (pr_ >= H ? 2*H-2-pr_ : pr_); \
        const float* tb_ = tc + (size_t)tr_ * W;                                     \
        const float* pb_ = pc + (size_t)pr_ * W;                                     \
        float2 a_ = *(const float2*)(tb_ + oa), b_ = *(const float2*)(tb_ + c0),     \
               c_ = *(const float2*)(tb_ + oc);                                      \
        t6[0]=a_.x; t6[1]=a_.y; t6[2]=b_.x; t6[3]=b_.y; t6[4]=c_.x; t6[5]=c_.y;      \
        a_ = *(const float2*)(pb_ + oa); b_ = *(const float2*)(pb_ + c0);            \
        c_ = *(const float2*)(pb_ + oc);                                             \
        p6[0]=a_.x; p6[1]=a_.y; p6[2]=b_.x; p6[3]=b_.y; p6[4]=c_.x; p6[5]=c_.y;      \
        float g0_ = t6[0];                                                           \
        t6[0] = eL ? t6[1] : t6[0];                                                  \
        t6[1] = eL ? g0_   : t6[1];                                                  \
        float g4_ = t6[4];                                                           \
        t6[4] = eR ? t6[5] : t6[4];                                                  \
        t6[5] = eR ? g4_   : t6[5]; }

    // consume pending row into P slot K (static), eh[2], tch[2] (after shift)
    #define CONSUME(K) {                                                             \
        eh[0][0]=eh[1][0]; eh[0][1]=eh[1][1]; eh[0][2]=eh[1][2]; eh[0][3]=eh[1][3];  \
        eh[1][0]=eh[2][0]; eh[1][1]=eh[2][1]; eh[1][2]=eh[2][2]; eh[1][3]=eh[2][3];  \
        tch[0][0]=tch[1][0]; tch[0][1]=tch[1][1];                                    \
        tch[1][0]=tch[2][0]; tch[1][1]=tch[2][1];                                    \
        float s04 = t6[0] + t6[4], s13 = t6[1] + t6[3];                              \
        P1h[K][0] = fmaf(-2.f, t6[2], s04);                                          \
        P3h[K][0] = fmaf(6.f, t6[2], fmaf(4.f, s13, s04));                           \
        P2h[K][0] = fmaf(2.f, t6[3] - t6[1], t6[4] - t6[0]);                         \
        float s04b = t6[1] + t6[5], s13b = t6[2] + t6[4];                            \
        P1h[K][1] = fmaf(-2.f, t6[3], s04b);                                         \
        P3h[K][1] = fmaf(6.f, t6[3], fmaf(4.f, s13b, s04b));                         \
        P2h[K][1] = fmaf(2.f, t6[4] - t6[2], t6[5] - t6[1]);                         \
        P1h[K][0] = fmaf(eL2, t6[2] - t6[3], P1h[K][0]);                             \
        P1h[K][1] = fmaf(eR2, t6[3] - t6[2], P1h[K][1]);                             \
        tch[2][0] = t6[2]; tch[2][1] = t6[3];                                        \
        eh[2][0] = __expf(0.1f * p6[1]);                                             \
        eh[2][1] = __expf(0.1f * p6[2]);                                             \
        eh[2][2] = __expf(0.1f * p6[3]);                                             \
        eh[2][3] = __expf(0.1f * p6[4]); }

    // output row y = y0 + I - 4; P slots static per K (s4 = K newest = row y+2)
    #define OUTPUT(I, K) if ((I) >= 4) {                                             \
        const int y = y0 + (I) - 4;                                                  \
        const int s0=((K)+1)%5, s1=((K)+2)%5, s2=((K)+3)%5, s3=((K)+4)%5, s4=(K);    \
        const bool ytop = (y == 0), ybot = (y == H - 1);                             \
        _Pragma("unroll")                                                            \
        for (int j = 0; j < 2; ++j) {                                                \
            float a04 = P1h[s0][j] + P1h[s4][j], a13 = P1h[s1][j] + P1h[s3][j];      \
            float xx = fmaf(6.f, P1h[s2][j], fmaf(4.f, a13, a04));                   \
            float xy = fmaf(2.f, P2h[s3][j] - P2h[s1][j], P2h[s4][j] - P2h[s0][j]);  \
            float yy = fmaf(-2.f, P3h[s2][j], P3h[s0][j] + P3h[s4][j]);              \
            if (ytop) {                                                              \
                xx += P1h[s3][j] - P1h[s2][j];                                       \
                xy += P2h[s3][j] - P2h[s2][j];                                       \
                yy += P3h[s2][j] - P3h[s3][j];                                       \
            } else if (ybot) {                                                       \
                xx += P1h[s1][j] - P1h[s2][j];                                       \
                xy += P2h[s2][j] - P2h[s1][j];                                       \
                yy += P3h[s2][j] - P3h[s1][j];                                       \
            }                                                                        \
            if (tch[0][j] > 0.f) {                                                   \
                float den = xx + 6.4e-6f;                                            \
                float sa  = 6.4e-6f - xy;                                            \
                float ax = fabsf(den), ay = fabsf(yy);                               \
                bool isH = ay < 0.41421356f * ax;                                    \
                bool isV = ay >= 2.41421356f * ax;                                   \
                bool qp  = ((yy * sa) * den) > 0.f;                                  \
                float ec = eh[1][j + 1];                                             \
                float n1 = isH ? eh[1][j + 2] : (isV ? eh[2][j + 1]                  \
                                : (qp ? eh[2][j] : eh[2][j + 2]));                   \
                float n2 = isH ? eh[1][j]     : (isV ? eh[0][j + 1]                  \
                                : (qp ? eh[0][j + 2] : eh[0][j]));                   \
                partial += __logf(__fdividef(ec, ec + n1 + n2 + 1e-7f));             \
            }                                                                        \
        } }

    LOADROW(0)

    float partial = 0.f;

    // rolled outer loop x 5-copy inner body: ~4KB hot code, all ring indices static
    #pragma unroll 1
    for (int mm = 0; mm < 4; ++mm) {
        #pragma unroll
        for (int k = 0; k < 5; ++k) {
            const int i = mm * 5 + k;
            CONSUME(k)
            if (i + 1 < NITER) LOADROW(i + 1)
            OUTPUT(i, k)
        }
    }

    // ---- block reduction: wave shuffle + spread atomics ----
    for (int off = 32; off > 0; off >>= 1)
        partial += __shfl_down(partial, off, 64);
    if (lane == 0) {
        int fid = (blockIdx.y * gridDim.x + blockIdx.x) * 4 + (tid >> 6);
        if (acc_d) atomicAdd(&acc_d[fid & (NSLOT - 1)], (double)partial);
        else       atomicAdd(acc_f, partial);
    }
}

__global__ void finalize_kernel(const double* acc_d, float* out,
                                int use_double, float inv_b)
{
    if (use_double) {
        int l = threadIdx.x;
        double s = 0.0;
        for (int i = l; i < NSLOT; i += 64) s += acc_d[i];
        for (int off = 32; off > 0; off >>= 1) s += __shfl_down(s, off, 64);
        if (l == 0) out[0] = (float)(-s * (double)inv_b);
    } else {
        if (threadIdx.x == 0) out[0] = -out[0] * inv_b;
    }
}

extern "C" void kernel_launch(void* const* d_in, const int* in_sizes, int n_in,
                              void* d_out, int out_size, void* d_ws, size_t ws_size,
                              hipStream_t stream)
{
    const float* tl = (const float*)d_in[0];
    const float* pl = (const float*)d_in[1];
    float* out = (float*)d_out;

    const int H = 512, W = 512, B = 4;

    double* acc_d = nullptr;
    float* acc_f = nullptr;
    int use_double = 0;
    if (ws_size >= NSLOT * sizeof(double)) {
        acc_d = (double*)d_ws;
        use_double = 1;
        hipMemsetAsync(acc_d, 0, NSLOT * sizeof(double), stream);
    } else {
        acc_f = out;
        hipMemsetAsync(out, 0, sizeof(float), stream);
    }

    dim3 grid(H / BAND, 76, 1);   // 32 bands x 76 channels, 512 cols/block
    nms_loss_kernel<<<grid, 256, 0, stream>>>(tl, pl, acc_d, acc_f, H, W);
    finalize_kernel<<<1, 64, 0, stream>>>(acc_d, out, use_double, 1.0f / (float)B);
}

// Round 20
// 58.001 us; speedup vs baseline: 2.0972x; 1.0574x over previous
//
#include <hip/hip_runtime.h>

#define BAND 8
#define NITER (BAND + 4)
#define NSLOT 1024

__global__ __launch_bounds__(256) void nms_loss_kernel(
    const float* __restrict__ tl, const float* __restrict__ pl,
    double* __restrict__ acc_d, float* __restrict__ acc_f,
    int H, int W)
{
    const int y0  = blockIdx.x * BAND;
    const int ch  = blockIdx.y;
    const float* tc = tl + (size_t)ch * H * W;
    const float* pc = pl + (size_t)ch * H * W;
    const int tid  = threadIdx.x;
    const int lane = tid & 63;
    const int c0 = tid << 1;                    // this thread's 2 output columns
    const int oa = min(max(c0 - 2, 0), W - 2);  // clamped float2 bases
    const int oc = min(c0 + 2, W - 2);
    const bool xedge = (c0 == 0) || (c0 == W - 2);

    // register rings: P (5 rows), e (3 rows), t-center/mask (3 rows), pending loads
    float P1h[5][2], P2h[5][2], P3h[5][2];
    float eh[3][4], tch[3][2];
    float t6[6], p6[6];

    // prologue: load t row y0-2 (clamp), p row y0-3 (reflect)
    {
        int tr = max(y0 - 2, 0);
        int pr = y0 - 3; pr = pr < 0 ? -pr : pr;
        const float* tb = tc + (size_t)tr * W;
        const float* pb = pc + (size_t)pr * W;
        float2 a = *(const float2*)(tb + oa), b = *(const float2*)(tb + c0), c = *(const float2*)(tb + oc);
        t6[0]=a.x; t6[1]=a.y; t6[2]=b.x; t6[3]=b.y; t6[4]=c.x; t6[5]=c.y;
        a = *(const float2*)(pb + oa); b = *(const float2*)(pb + c0); c = *(const float2*)(pb + oc);
        p6[0]=a.x; p6[1]=a.y; p6[2]=b.x; p6[3]=b.y; p6[4]=c.x; p6[5]=c.y;
    }

    float partial = 0.f;

    #pragma unroll
    for (int i = 0; i < NITER; ++i) {
        const int sP = i % 5, sE = i % 3;

        // ---- consume pending: t6 -> P(row y0-2+i) + mask; p6 -> e(row y0-3+i)
        if (!xedge) {
            float s04 = t6[0] + t6[4], s13 = t6[1] + t6[3];
            P1h[sP][0] = fmaf(-2.f, t6[2], s04);                        // hdd [1,0,-2,0,1]
            P3h[sP][0] = fmaf(6.f, t6[2], fmaf(4.f, s13, s04));          // hss [1,4,6,4,1]
            P2h[sP][0] = fmaf(2.f, t6[3] - t6[1], t6[4] - t6[0]);        // hds [-1,-2,0,2,1]
            float s04b = t6[1] + t6[5], s13b = t6[2] + t6[4];
            P1h[sP][1] = fmaf(-2.f, t6[3], s04b);
            P3h[sP][1] = fmaf(6.f, t6[3], fmaf(4.f, s13b, s04b));
            P2h[sP][1] = fmaf(2.f, t6[4] - t6[2], t6[5] - t6[1]);
        } else if (c0 == 0) {
            P1h[sP][0] = t6[4] - t6[3];                                  // [0,0,0,-1,1]
            P2h[sP][0] = fmaf(-2.f, t6[2], t6[3] + t6[4]);               // [0,0,-2,1,1]
            P3h[sP][0] = fmaf(10.f, t6[2], fmaf(5.f, t6[3], t6[4]));     // [0,0,10,5,1]
            P1h[sP][1] = fmaf(-2.f, t6[3], t6[2] + t6[5]);               // [0,1,-2,0,1]
            P2h[sP][1] = fmaf(-3.f, t6[2], fmaf(2.f, t6[4], t6[5]));     // [0,-3,0,2,1]
            P3h[sP][1] = fmaf(5.f, t6[2], fmaf(6.f, t6[3], fmaf(4.f, t6[4], t6[5]))); // [0,5,6,4,1]
        } else { // c0 == W-2
            P1h[sP][0] = fmaf(-2.f, t6[2], t6[0] + t6[3]);               // [1,0,-2,1,0]
            P2h[sP][0] = fmaf(3.f, t6[3], fmaf(-2.f, t6[1], -t6[0]));    // [-1,-2,0,3,0]
            P3h[sP][0] = fmaf(5.f, t6[3], fmaf(6.f, t6[2], fmaf(4.f, t6[1], t6[0]))); // [1,4,6,5,0]
            P1h[sP][1] = t6[1] - t6[2];                                  // [1,-1,0,0,0]
            P2h[sP][1] = fmaf(2.f, t6[3], -t6[1] - t6[2]);               // [-1,-1,2,0,0]
            P3h[sP][1] = fmaf(10.f, t6[3], fmaf(5.f, t6[2], t6[1]));     // [1,5,10,0,0]
        }
        tch[sE][0] = t6[2]; tch[sE][1] = t6[3];
        eh[sE][0] = __expf(0.1f * p6[1]);   // cols c0-1..c0+2 (edge reflect = auto via clamp)
        eh[sE][1] = __expf(0.1f * p6[2]);
        eh[sE][2] = __expf(0.1f * p6[3]);
        eh[sE][3] = __expf(0.1f * p6[4]);

        // ---- issue next row loads (consumed next iteration)
        if (i + 1 < NITER) {
            int tr = y0 - 1 + i;  tr = min(max(tr, 0), H - 1);
            int pr = y0 - 2 + i;  pr = pr < 0 ? -pr : (pr >= H ? 2 * H - 2 - pr : pr);
            const float* tb = tc + (size_t)tr * W;
            const float* pb = pc + (size_t)pr * W;
            float2 a = *(const float2*)(tb + oa), b = *(const float2*)(tb + c0), c = *(const float2*)(tb + oc);
            t6[0]=a.x; t6[1]=a.y; t6[2]=b.x; t6[3]=b.y; t6[4]=c.x; t6[5]=c.y;
            a = *(const float2*)(pb + oa); b = *(const float2*)(pb + c0); c = *(const float2*)(pb + oc);
            p6[0]=a.x; p6[1]=a.y; p6[2]=b.x; p6[3]=b.y; p6[4]=c.x; p6[5]=c.y;
        }

        // ---- output row y = y0 + i - 4
        if (i >= 4) {
            const int y = y0 + i - 4;
            const int s0 = (i - 4) % 5, s1 = (i - 3) % 5, s2 = (i - 2) % 5,
                      s3 = (i - 1) % 5, s4 = i % 5;
            float xx[2], xy[2], yy[2];
            if (y >= 2 && y <= H - 3) {
                #pragma unroll
                for (int j = 0; j < 2; ++j) {
                    float a04 = P1h[s0][j] + P1h[s4][j], a13 = P1h[s1][j] + P1h[s3][j];
                    xx[j] = fmaf(6.f, P1h[s2][j], fmaf(4.f, a13, a04));      // wss
                    xy[j] = fmaf(2.f, P2h[s3][j] - P2h[s1][j], P2h[s4][j] - P2h[s0][j]); // wsd
                    yy[j] = fmaf(-2.f, P3h[s2][j], P3h[s0][j] + P3h[s4][j]); // wdd
                }
            } else {
                float wss[5], wsd[5], wdd[5];
                if (y == 0) {
                    wss[0]=0; wss[1]=0; wss[2]=10; wss[3]=5;  wss[4]=1;
                    wsd[0]=0; wsd[1]=0; wsd[2]=-4; wsd[3]=3;  wsd[4]=1;
                    wdd[0]=0; wdd[1]=0; wdd[2]=0;  wdd[3]=-1; wdd[4]=1;
                } else if (y == 1) {
                    wss[0]=0; wss[1]=5; wss[2]=6;  wss[3]=4;  wss[4]=1;
                    wsd[0]=0; wsd[1]=-3;wsd[2]=0;  wsd[3]=2;  wsd[4]=1;
                    wdd[0]=0; wdd[1]=1; wdd[2]=-2; wdd[3]=0;  wdd[4]=1;
                } else if (y == H - 1) {
                    wss[0]=1; wss[1]=5; wss[2]=10; wss[3]=0;  wss[4]=0;
                    wsd[0]=-1;wsd[1]=-3;wsd[2]=4;  wsd[3]=0;  wsd[4]=0;
                    wdd[0]=1; wdd[1]=-1;wdd[2]=0;  wdd[3]=0;  wdd[4]=0;
                } else { // y == H-2
                    wss[0]=1; wss[1]=4; wss[2]=6;  wss[3]=5;  wss[4]=0;
                    wsd[0]=-1;wsd[1]=-2;wsd[2]=0;  wsd[3]=3;  wsd[4]=0;
                    wdd[0]=1; wdd[1]=0; wdd[2]=-2; wdd[3]=1;  wdd[4]=0;
                }
                const int ss[5] = {s0, s1, s2, s3, s4};
                #pragma unroll
                for (int j = 0; j < 2; ++j) {
                    float X = 0.f, Y = 0.f, Z = 0.f;
                    #pragma unroll
                    for (int k = 0; k < 5; ++k) {
                        X = fmaf(wss[k], P1h[ss[k]][j], X);
                        Y = fmaf(wsd[k], P2h[ss[k]][j], Y);
                        Z = fmaf(wdd[k], P3h[ss[k]][j], Z);
                    }
                    xx[j] = X; xy[j] = Y; yy[j] = Z;
                }
            }

            const int et = (i - 2) % 3, em = (i - 1) % 3, eb = i % 3; // rows y-1, y, y+1
            #pragma unroll
            for (int j = 0; j < 2; ++j) {
                if (tch[et][j] > 0.f) {          // mask row y (ring slot (i-2)%3)
                    float den = xx[j] + 6.4e-6f;  // 64*(grad_xx+1e-7)
                    float sa  = 6.4e-6f - xy[j];  // 64*(1e-7-grad_xy)
                    float ax = fabsf(den), ay = fabsf(yy[j]);
                    bool isH = ay < 0.41421356f * ax;    // tan(22.5)
                    bool isV = ay >= 2.41421356f * ax;   // tan(67.5)
                    bool qp  = ((yy[j] * sa) * den) > 0.f;
                    float ec = eh[em][j + 1];
                    float n1 = isH ? eh[em][j + 2] : (isV ? eh[eb][j + 1] : (qp ? eh[eb][j] : eh[eb][j + 2]));
                    float n2 = isH ? eh[em][j]     : (isV ? eh[et][j + 1] : (qp ? eh[et][j + 2] : eh[et][j]));
                    partial += __logf(__fdividef(ec, ec + n1 + n2 + 1e-7f));
                }
            }
        }
    }

    // ---- wave reduction + spread atomics (no barriers anywhere) ----
    for (int off = 32; off > 0; off >>= 1)
        partial += __shfl_down(partial, off, 64);
    if (lane == 0) {
        int fid = (blockIdx.y * gridDim.x + blockIdx.x) * 4 + (tid >> 6);
        if (acc_d) atomicAdd(&acc_d[fid & (NSLOT - 1)], (double)partial);
        else       atomicAdd(acc_f, partial);
    }
}

__global__ void finalize_kernel(const double* acc_d, float* out,
                                int use_double, float inv_b)
{
    if (use_double) {
        int l = threadIdx.x;
        double s = 0.0;
        for (int i = l; i < NSLOT; i += 64) s += acc_d[i];
        for (int off = 32; off > 0; off >>= 1) s += __shfl_down(s, off, 64);
        if (l == 0) out[0] = (float)(-s * (double)inv_b);
    } else {
        if (threadIdx.x == 0) out[0] = -out[0] * inv_b;
    }
}

extern "C" void kernel_launch(void* const* d_in, const int* in_sizes, int n_in,
                              void* d_out, int out_size, void* d_ws, size_t ws_size,
                              hipStream_t stream)
{
    const float* tl = (const float*)d_in[0];
    const float* pl = (const float*)d_in[1];
    float* out = (float*)d_out;

    const int H = 512, W = 512, B = 4;

    double* acc_d = nullptr;
    float* acc_f = nullptr;
    int use_double = 0;
    if (ws_size >= NSLOT * sizeof(double)) {
        acc_d = (double*)d_ws;
        use_double = 1;
        hipMemsetAsync(acc_d, 0, NSLOT * sizeof(double), stream);
    } else {
        acc_f = out;
        hipMemsetAsync(out, 0, sizeof(float), stream);
    }

    dim3 grid(H / BAND, 76, 1);   // 64 bands x 76 channels = 4864 blocks (19456 waves)
    nms_loss_kernel<<<grid, 256, 0, stream>>>(tl, pl, acc_d, acc_f, H, W);
    finalize_kernel<<<1, 64, 0, stream>>>(acc_d, out, use_double, 1.0f / (float)B);
}

// Round 21
// 54.966 us; speedup vs baseline: 2.2130x; 1.0552x over previous
//
#include <hip/hip_runtime.h>

#define BAND 8
#define NITER (BAND + 4)
#define NSLOT 1024

typedef float v2f __attribute__((ext_vector_type(2)));

__device__ __forceinline__ v2f fma2k(float k, v2f a, v2f b) {
    v2f vk = {k, k};
    return __builtin_elementwise_fma(vk, a, b);   // -> v_pk_fma_f32
}

__global__ __launch_bounds__(256) void nms_loss_kernel(
    const float* __restrict__ tl, const float* __restrict__ pl,
    double* __restrict__ acc_d, float* __restrict__ acc_f,
    int H, int W)
{
    const int y0  = blockIdx.x * BAND;
    const int ch  = blockIdx.y;
    const float* tc = tl + (size_t)ch * H * W;
    const float* pc = pl + (size_t)ch * H * W;
    const int tid  = threadIdx.x;
    const int lane = tid & 63;
    const int c0 = tid << 1;                    // 2 output columns per thread
    const int oa = min(max(c0 - 2, 0), W - 2);  // clamped float2 bases
    const int oc = min(c0 + 2, W - 2);
    const bool eL = (c0 == 0), eR = (c0 == W - 2);
    const float eL2 = eL ? 2.f : 0.f, eR2 = eR ? 2.f : 0.f;

    // rings: P (5 rows, v2f = j-pair packed), e (3 rows), mask (3 rows)
    v2f P1v[5], P2v[5], P3v[5];
    float eh[3][4];
    v2f tch[3];
    float t6[6], p6[6];

    // t row y0-2+I (clamp), p row y0-3+I (reflect); t-edge ghosts via swap
    // (R18-validated); p-edge reflect ghosts automatic from clamped base.
    #define LOADROW(I) {                                                            \
        int tr_ = y0 - 2 + (I); tr_ = min(max(tr_, 0), H - 1);                       \
        int pr_ = y0 - 3 + (I); pr_ = pr_ < 0 ? -pr_ : (pr_ >= H ? 2*H-2-pr_ : pr_); \
        const float* tb_ = tc + (size_t)tr_ * W;                                     \
        const float* pb_ = pc + (size_t)pr_ * W;                                     \
        float2 a_ = *(const float2*)(tb_ + oa), b_ = *(const float2*)(tb_ + c0),     \
               c_ = *(const float2*)(tb_ + oc);                                      \
        t6[0]=a_.x; t6[1]=a_.y; t6[2]=b_.x; t6[3]=b_.y; t6[4]=c_.x; t6[5]=c_.y;      \
        a_ = *(const float2*)(pb_ + oa); b_ = *(const float2*)(pb_ + c0);            \
        c_ = *(const float2*)(pb_ + oc);                                             \
        p6[0]=a_.x; p6[1]=a_.y; p6[2]=b_.x; p6[3]=b_.y; p6[4]=c_.x; p6[5]=c_.y;      \
        float g0_ = t6[0];                                                           \
        t6[0] = eL ? t6[1] : t6[0];                                                  \
        t6[1] = eL ? g0_   : t6[1];                                                  \
        float g4_ = t6[4];                                                           \
        t6[4] = eR ? t6[5] : t6[4];                                                  \
        t6[5] = eR ? g4_   : t6[5]; }

    // consume pending row into P slot SP (packed), eh/tch slot SE
    #define CONSUME(SP, SE) {                                                        \
        v2f Av = {t6[0], t6[1]}, Bv = {t6[1], t6[2]}, Cv = {t6[2], t6[3]};           \
        v2f Dv = {t6[3], t6[4]}, Ev = {t6[4], t6[5]};                                \
        v2f s04 = Av + Ev, s13 = Bv + Dv;                                            \
        P1v[SP] = fma2k(-2.f, Cv, s04);                       /* hdd */              \
        P3v[SP] = fma2k(6.f, Cv, fma2k(4.f, s13, s04));       /* hss */              \
        P2v[SP] = fma2k(2.f, Dv - Bv, Ev - Av);               /* hds */              \
        P1v[SP].x = fmaf(eL2, t6[2] - t6[3], P1v[SP].x);      /* edge residuals */   \
        P1v[SP].y = fmaf(eR2, t6[3] - t6[2], P1v[SP].y);                             \
        tch[SE] = Cv;                                                                \
        eh[SE][0] = __expf(0.1f * p6[1]);                                            \
        eh[SE][1] = __expf(0.1f * p6[2]);                                            \
        eh[SE][2] = __expf(0.1f * p6[3]);                                            \
        eh[SE][3] = __expf(0.1f * p6[4]); }

    // output row y = y0 + I - 4 (packed V-pass + R18-validated y-edge fixups)
    #define OUTPUT(I) if ((I) >= 4) {                                                \
        const int y = y0 + (I) - 4;                                                  \
        const int s0=((I)-4)%5, s1=((I)-3)%5, s2=((I)-2)%5, s3=((I)-1)%5, s4=(I)%5;  \
        const int et=((I)-2)%3, em=((I)-1)%3, ebq=(I)%3;                             \
        const bool ytop = (y == 0), ybot = (y == H - 1);                             \
        v2f a04 = P1v[s0] + P1v[s4], a13 = P1v[s1] + P1v[s3];                        \
        v2f xx = fma2k(6.f, P1v[s2], fma2k(4.f, a13, a04));                          \
        v2f xy = fma2k(2.f, P2v[s3] - P2v[s1], P2v[s4] - P2v[s0]);                   \
        v2f yy = fma2k(-2.f, P3v[s2], P3v[s0] + P3v[s4]);                            \
        if (ytop) {                                                                  \
            xx += P1v[s3] - P1v[s2];                                                 \
            xy += P2v[s3] - P2v[s2];                                                 \
            yy += P3v[s2] - P3v[s3];                                                 \
        } else if (ybot) {                                                           \
            xx += P1v[s1] - P1v[s2];                                                 \
            xy += P2v[s2] - P2v[s1];                                                 \
            yy += P3v[s2] - P3v[s1];                                                 \
        }                                                                            \
        v2f den = xx + 6.4e-6f;                                                      \
        v2f sa  = 6.4e-6f - xy;                                                      \
        _Pragma("unroll")                                                            \
        for (int j = 0; j < 2; ++j) {                                                \
            float tcv = j ? tch[et].y : tch[et].x;                                   \
            if (tcv > 0.f) {                                                         \
                float dj = j ? den.y : den.x;                                        \
                float sj = j ? sa.y  : sa.x;                                         \
                float yj = j ? yy.y  : yy.x;                                         \
                float ax = fabsf(dj), ay = fabsf(yj);                                \
                bool isH = ay < 0.41421356f * ax;                                    \
                bool isV = ay >= 2.41421356f * ax;                                   \
                bool qp  = ((yj * sj) * dj) > 0.f;                                   \
                float ec = eh[em][j + 1];                                            \
                float n1 = isH ? eh[em][j + 2] : (isV ? eh[ebq][j + 1]               \
                                : (qp ? eh[ebq][j] : eh[ebq][j + 2]));               \
                float n2 = isH ? eh[em][j]     : (isV ? eh[et][j + 1]                \
                                : (qp ? eh[et][j + 2] : eh[et][j]));                 \
                partial += __logf(__fdividef(ec, ec + n1 + n2 + 1e-7f));             \
            }                                                                        \
        } }

    LOADROW(0)

    float partial = 0.f;

    #pragma unroll
    for (int i = 0; i < NITER; ++i) {
        CONSUME(i % 5, i % 3)
        if (i + 1 < NITER) LOADROW(i + 1)
        OUTPUT(i)
    }

    // ---- wave reduction + spread atomics (no barriers anywhere) ----
    for (int off = 32; off > 0; off >>= 1)
        partial += __shfl_down(partial, off, 64);
    if (lane == 0) {
        int fid = (blockIdx.y * gridDim.x + blockIdx.x) * 4 + (tid >> 6);
        if (acc_d) atomicAdd(&acc_d[fid & (NSLOT - 1)], (double)partial);
        else       atomicAdd(acc_f, partial);
    }
}

__global__ void finalize_kernel(const double* acc_d, float* out,
                                int use_double, float inv_b)
{
    if (use_double) {
        int l = threadIdx.x;
        double s = 0.0;
        for (int i = l; i < NSLOT; i += 64) s += acc_d[i];
        for (int off = 32; off > 0; off >>= 1) s += __shfl_down(s, off, 64);
        if (l == 0) out[0] = (float)(-s * (double)inv_b);
    } else {
        if (threadIdx.x == 0) out[0] = -out[0] * inv_b;
    }
}

extern "C" void kernel_launch(void* const* d_in, const int* in_sizes, int n_in,
                              void* d_out, int out_size, void* d_ws, size_t ws_size,
                              hipStream_t stream)
{
    const float* tl = (const float*)d_in[0];
    const float* pl = (const float*)d_in[1];
    float* out = (float*)d_out;

    const int H = 512, W = 512, B = 4;

    double* acc_d = nullptr;
    float* acc_f = nullptr;
    int use_double = 0;
    if (ws_size >= NSLOT * sizeof(double)) {
        acc_d = (double*)d_ws;
        use_double = 1;
        hipMemsetAsync(acc_d, 0, NSLOT * sizeof(double), stream);
    } else {
        acc_f = out;
        hipMemsetAsync(out, 0, sizeof(float), stream);
    }

    dim3 grid(H / BAND, 76, 1);   // 64 bands x 76 channels = 4864 blocks (19456 waves)
    nms_loss_kernel<<<grid, 256, 0, stream>>>(tl, pl, acc_d, acc_f, H, W);
    finalize_kernel<<<1, 64, 0, stream>>>(acc_d, out, use_double, 1.0f / (float)B);
}